// Round 2
// baseline (2033.158 us; speedup 1.0000x reference)
//
#include <hip/hip_runtime.h>
#include <hip/hip_fp16.h>
#include <stdint.h>

// PrunedInt4Linear: y = x @ dequant(q, scales)^T + bias
// x: [8192, 4096] f32
// q: [11008, 64, 64] codes in [-8,7]  (memory dtype sniffed: int8 or int32)
// scales: [11008, 64], bias: [11008]  (memory dtype sniffed: f16 or f32)
// y: [8192, 11008] f32
//
// Round 2 = correctness-first: single fused kernel, no workspace, no
// global_load_lds, no perm tricks, bf16 MFMA (m91/m97-verified layout).

#define M_DIM 8192
#define N_DIM 11008
#define K_DIM 4096
#define NT_TILES (N_DIM / 128)   // 86
#define MT_TILES (M_DIM / 128)   // 64

typedef short short8 __attribute__((ext_vector_type(8)));   // 8 bf16
typedef float floatx4 __attribute__((ext_vector_type(4)));

// f32 -> bf16, round-to-nearest-even
__device__ __forceinline__ unsigned short f2bf(float f) {
  union { float f; uint32_t u; } c; c.f = f;
  uint32_t u = c.u;
  uint32_t r = (u + 0x7FFFu + ((u >> 16) & 1u)) >> 16;
  return (unsigned short)r;
}

__device__ __forceinline__ float load_sc(const void* p, size_t idx, bool is_f32) {
  if (is_f32) return ((const float*)p)[idx];
  return __half2float(((const __half*)p)[idx]);
}

__global__ __launch_bounds__(256)
void gemm_fused(const float* __restrict__ x, const void* __restrict__ qv,
                const void* __restrict__ sv, const void* __restrict__ bv,
                float* __restrict__ C) {
  __shared__ __align__(16) short As[128 * 64];
  __shared__ __align__(16) short Bs[128 * 64];

  // ---- dtype sniff (uniform across all blocks/threads, deterministic) ----
  bool q_is_i32;
  {
    const int* w = (const int*)qv;   // 64 bytes, in-bounds for either dtype
    bool ok = true;
    #pragma unroll
    for (int j = 0; j < 16; ++j) {
      int v = w[j];
      ok = ok && (v == (int)(signed char)(v & 0xFF));   // sign-extended byte?
    }
    q_is_i32 = ok;   // real int8 codes pass all 16 with prob ~4096^-16
  }
  bool s_is_f32;
  {
    const float* f = (const float*)sv;  // 32 bytes, in-bounds for either dtype
    bool ok = true;
    #pragma unroll
    for (int j = 0; j < 8; ++j) {
      float v = f[j];
      ok = ok && (v > 4e-4f) && (v < 6e-2f);  // scales are in [1e-3, 2.1e-2]
    }
    s_is_f32 = ok;   // f16 pairs read as f32 give ~1e-27..1e-16 -> fails
  }

  const int tid  = threadIdx.x;
  const int lane = tid & 63;
  const int wid  = tid >> 6;
  const int wm = wid >> 1, wn = wid & 1;   // 2x2 wave grid, 64x64 out each
  const int lr = lane & 15, lk = lane >> 4;

  // XCD-aware swizzle (5504 % 8 == 0 -> bijective), then GM=4 m-grouping
  const int nwg = gridDim.x;               // 5504
  const int cpx = nwg >> 3;                // 688
  const int bid = blockIdx.x;
  const int swz = (bid & 7) * cpx + (bid >> 3);
  const int per_g = 4 * NT_TILES;          // 344
  const int g = swz / per_g;
  const int r = swz - g * per_g;
  const int mt = (g << 2) + (r & 3);       // [0,64)
  const int nt = r >> 2;                   // [0,86)

  const int row0 = mt * 128;
  const int col0 = nt * 128;

  floatx4 acc[4][4];
  #pragma unroll
  for (int i = 0; i < 4; ++i)
    #pragma unroll
    for (int j = 0; j < 4; ++j)
      acc[i][j] = (floatx4){0.f, 0.f, 0.f, 0.f};

  for (int kt = 0; kt < K_DIM / 64; ++kt) {
    const int k0 = kt * 64;

    // ---- stage A tile [128 m][64 k]: f32 -> bf16, reg -> ds_write ----
    #pragma unroll
    for (int i = 0; i < 4; ++i) {
      const int cid  = i * 256 + tid;          // [0,1024), 8 elems each
      const int arow = cid >> 3;
      const int ac   = (cid & 7) << 3;
      const float4* p = (const float4*)(x + (size_t)(row0 + arow) * K_DIM + k0 + ac);
      float4 a = p[0], b = p[1];
      short8 h;
      h[0] = f2bf(a.x); h[1] = f2bf(a.y); h[2] = f2bf(a.z); h[3] = f2bf(a.w);
      h[4] = f2bf(b.x); h[5] = f2bf(b.y); h[6] = f2bf(b.z); h[7] = f2bf(b.w);
      *(short8*)&As[arow * 64 + ac] = h;
    }

    // ---- stage B tile [128 n][64 k]: dequant q*s -> bf16 ----
    #pragma unroll
    for (int i = 0; i < 2; ++i) {
      const int cid  = i * 256 + tid;          // [0,512), 16 codes each
      const int brow = cid >> 2;
      const int bc   = (cid & 3) << 4;
      const float s = load_sc(sv, (size_t)(col0 + brow) * 64 + kt, s_is_f32);

      int codes[16];
      if (q_is_i32) {
        const int* qq = (const int*)qv + (size_t)(col0 + brow) * K_DIM + k0 + bc;
        #pragma unroll
        for (int j = 0; j < 4; ++j) {
          int4 t = ((const int4*)qq)[j];
          codes[j*4+0] = t.x; codes[j*4+1] = t.y;
          codes[j*4+2] = t.z; codes[j*4+3] = t.w;
        }
      } else {
        const int8_t* qq = (const int8_t*)qv + (size_t)(col0 + brow) * K_DIM + k0 + bc;
        union { int4 v; int8_t b[16]; } u;
        u.v = *(const int4*)qq;
        #pragma unroll
        for (int j = 0; j < 16; ++j) codes[j] = (int)u.b[j];
      }

      short8 h0, h1;
      #pragma unroll
      for (int j = 0; j < 8; ++j) h0[j] = f2bf((float)codes[j] * s);
      #pragma unroll
      for (int j = 0; j < 8; ++j) h1[j] = f2bf((float)codes[8 + j] * s);
      *(short8*)&Bs[brow * 64 + bc]     = h0;
      *(short8*)&Bs[brow * 64 + bc + 8] = h1;
    }

    __syncthreads();

    // ---- MFMA: 16x16x32 bf16, m97-verified fragment layout ----
    #pragma unroll
    for (int ks = 0; ks < 2; ++ks) {
      short8 a[4], b[4];
      #pragma unroll
      for (int mi = 0; mi < 4; ++mi)
        a[mi] = *(const short8*)&As[(wm * 64 + mi * 16 + lr) * 64 + ks * 32 + lk * 8];
      #pragma unroll
      for (int ni = 0; ni < 4; ++ni)
        b[ni] = *(const short8*)&Bs[(wn * 64 + ni * 16 + lr) * 64 + ks * 32 + lk * 8];
      #pragma unroll
      for (int mi = 0; mi < 4; ++mi)
        #pragma unroll
        for (int ni = 0; ni < 4; ++ni)
          acc[mi][ni] = __builtin_amdgcn_mfma_f32_16x16x32_bf16(
              a[mi], b[ni], acc[mi][ni], 0, 0, 0);
    }

    __syncthreads();
  }

  // epilogue: C/D layout col = lane&15, row = (lane>>4)*4 + reg (m89/m91)
  #pragma unroll
  for (int ni = 0; ni < 4; ++ni) {
    const int col = col0 + wn * 64 + ni * 16 + lr;
    const float bvf = load_sc(bv, (size_t)col, s_is_f32);
    #pragma unroll
    for (int mi = 0; mi < 4; ++mi) {
      const int rbase = row0 + wm * 64 + mi * 16 + lk * 4;
      #pragma unroll
      for (int rr = 0; rr < 4; ++rr)
        C[(size_t)(rbase + rr) * N_DIM + col] = acc[mi][ni][rr] + bvf;
    }
  }
}

extern "C" void kernel_launch(void* const* d_in, const int* in_sizes, int n_in,
                              void* d_out, int out_size, void* d_ws, size_t ws_size,
                              hipStream_t stream) {
  const float* x  = (const float*)d_in[0];
  const void*  q  = (const void*)d_in[1];
  const void*  sc = (const void*)d_in[2];
  const void*  bs = (const void*)d_in[3];
  float* y = (float*)d_out;

  (void)d_ws; (void)ws_size; (void)in_sizes; (void)n_in; (void)out_size;

  dim3 blk(256);
  gemm_fused<<<MT_TILES * NT_TILES, blk, 0, stream>>>(x, q, sc, bs, y);
}

// Round 3
// 1185.552 us; speedup vs baseline: 1.7149x; 1.7149x over previous
//
#include <hip/hip_runtime.h>
#include <hip/hip_fp16.h>
#include <stdint.h>

// PrunedInt4Linear: y = x @ dequant(q, scales)^T + bias
// x: [8192, 4096] f32
// q: [11008, 64, 64] codes in [-8,7]  (memory dtype sniffed: int8 or int32)
// scales: [11008, 64], bias: [11008]  (memory dtype sniffed: f16 or f32;
//                                      round-1 forensics says f32)
// y: [8192, 11008] f32
//
// Round 3: pre-dequant W -> bf16 and pre-convert x -> bf16 into d_ws (prep
// kernels, memory-bound), then m97-structure bf16 GEMM with global_load_lds
// width-16 on both operands. Fallbacks (ws too small) reuse the round-2
// verified fused staging paths.

#define M_DIM 8192
#define N_DIM 11008
#define K_DIM 4096
#define NT_TILES (N_DIM / 128)   // 86
#define MT_TILES (M_DIM / 128)   // 64

typedef short short8 __attribute__((ext_vector_type(8)));   // 8 bf16
typedef float floatx4 __attribute__((ext_vector_type(4)));

// f32 -> bf16, round-to-nearest-even
__device__ __forceinline__ unsigned short f2bf(float f) {
  union { float f; uint32_t u; } c; c.f = f;
  uint32_t u = c.u;
  uint32_t r = (u + 0x7FFFu + ((u >> 16) & 1u)) >> 16;
  return (unsigned short)r;
}

__device__ __forceinline__ float load_sc(const void* p, size_t idx, bool is_f32) {
  if (is_f32) return ((const float*)p)[idx];
  return __half2float(((const __half*)p)[idx]);
}

// ---- dtype sniffs (uniform across all threads, deterministic; verified r2) ----
__device__ __forceinline__ bool sniff_q_is_i32(const void* qv) {
  const int* w = (const int*)qv;   // 64 bytes, in-bounds for either dtype
  bool ok = true;
  #pragma unroll
  for (int j = 0; j < 16; ++j) {
    int v = w[j];
    ok = ok && (v == (int)(signed char)(v & 0xFF));   // sign-extended byte?
  }
  return ok;
}
__device__ __forceinline__ bool sniff_s_is_f32(const void* sv) {
  const float* f = (const float*)sv;  // 32 bytes, in-bounds for either dtype
  bool ok = true;
  #pragma unroll
  for (int j = 0; j < 8; ++j) {
    float v = f[j];
    ok = ok && (v > 4e-4f) && (v < 6e-2f);  // scales are in [1e-3, 2.1e-2]
  }
  return ok;
}

// async global -> LDS, 16B per lane (m97 pattern; LDS dest must be linear)
__device__ __forceinline__ void gload_lds16(const void* g, void* l) {
  __builtin_amdgcn_global_load_lds(
      (const __attribute__((address_space(1))) uint32_t*)g,
      (__attribute__((address_space(3))) uint32_t*)l, 16, 0, 0);
}

// ---- prep: x f32 -> bf16 (8 elems / thread, exact grid) ----
__global__ __launch_bounds__(256)
void cvt_x_kernel(const float* __restrict__ x, short* __restrict__ xh) {
  size_t i = (size_t)blockIdx.x * 256 + threadIdx.x;   // 8-float chunk id
  const float4* p = (const float4*)x + i * 2;
  float4 a = p[0], b = p[1];
  short8 h;
  h[0] = f2bf(a.x); h[1] = f2bf(a.y); h[2] = f2bf(a.z); h[3] = f2bf(a.w);
  h[4] = f2bf(b.x); h[5] = f2bf(b.y); h[6] = f2bf(b.z); h[7] = f2bf(b.w);
  ((short8*)xh)[i] = h;
}

// ---- prep: W codes + scales -> bf16 (16 codes / thread, exact grid) ----
__global__ __launch_bounds__(256)
void deq_w_kernel(const void* __restrict__ qv, const void* __restrict__ sv,
                  short* __restrict__ wq) {
  const bool q_is_i32 = sniff_q_is_i32(qv);
  const bool s_is_f32 = sniff_s_is_f32(sv);

  size_t cid = (size_t)blockIdx.x * 256 + threadIdx.x; // 16-code chunk id
  int row = (int)(cid >> 8);            // 256 chunks per row (4096/16)
  int k16 = (int)(cid & 255);
  const float s = load_sc(sv, (size_t)row * 64 + (k16 >> 2), s_is_f32);

  int codes[16];
  if (q_is_i32) {
    const int* qq = (const int*)qv + cid * 16;
    #pragma unroll
    for (int j = 0; j < 4; ++j) {
      int4 t = ((const int4*)qq)[j];
      codes[j*4+0] = t.x; codes[j*4+1] = t.y;
      codes[j*4+2] = t.z; codes[j*4+3] = t.w;
    }
  } else {
    union { int4 v; int8_t b[16]; } u;
    u.v = ((const int4*)qv)[cid];
    #pragma unroll
    for (int j = 0; j < 16; ++j) codes[j] = (int)u.b[j];
  }

  short8 h0, h1;
  #pragma unroll
  for (int j = 0; j < 8; ++j) h0[j] = f2bf((float)codes[j] * s);
  #pragma unroll
  for (int j = 0; j < 8; ++j) h1[j] = f2bf((float)codes[8 + j] * s);
  ((short8*)wq)[cid * 2]     = h0;
  ((short8*)wq)[cid * 2 + 1] = h1;
}

// ---- GEMM: 128x128 tile, BK=64, 4 waves (2x2), mfma_f32_16x16x32_bf16 ----
// PREA: A pre-converted bf16 (global_load_lds). else: x f32, convert + ds_write.
// PREB: W pre-dequantized bf16 (global_load_lds). else: fused dequant + ds_write.
template <bool PREA, bool PREB>
__global__ __launch_bounds__(256)
void gemm_kernel(const void* __restrict__ Av, const short* __restrict__ Bh,
                 const void* __restrict__ qv, const void* __restrict__ sv,
                 const void* __restrict__ bv, float* __restrict__ C) {
  __shared__ __align__(16) short As[128 * 64];
  __shared__ __align__(16) short Bs[128 * 64];

  const bool s_is_f32 = sniff_s_is_f32(sv);
  bool q_is_i32 = false;
  if constexpr (!PREB) q_is_i32 = sniff_q_is_i32(qv);

  const int tid  = threadIdx.x;
  const int lane = tid & 63;
  const int wid  = tid >> 6;
  const int wm = wid >> 1, wn = wid & 1;   // 2x2 wave grid, 64x64 out each
  const int lr = lane & 15, lk = lane >> 4;

  // XCD-aware swizzle (5504 % 8 == 0 -> bijective), then GM=4 m-grouping
  const int nwg = gridDim.x;               // 5504
  const int cpx = nwg >> 3;                // 688
  const int bid = blockIdx.x;
  const int swz = (bid & 7) * cpx + (bid >> 3);
  const int per_g = 4 * NT_TILES;          // 344
  const int g = swz / per_g;
  const int r = swz - g * per_g;
  const int mt = (g << 2) + (r & 3);       // [0,64)
  const int nt = r >> 2;                   // [0,86)

  const int row0 = mt * 128;
  const int col0 = nt * 128;

  const short* Ah = (const short*)Av;
  const float* Af = (const float*)Av;

  floatx4 acc[4][4];
  #pragma unroll
  for (int i = 0; i < 4; ++i)
    #pragma unroll
    for (int j = 0; j < 4; ++j)
      acc[i][j] = (floatx4){0.f, 0.f, 0.f, 0.f};

  for (int kt = 0; kt < K_DIM / 64; ++kt) {
    const int k0 = kt * 64;

    // ---- stage A tile [128 m][64 k] ----
    if constexpr (PREA) {
      #pragma unroll
      for (int i = 0; i < 4; ++i) {
        const int cid = i * 256 + tid;               // 8-bf16 chunk
        const int arow = cid >> 3, ac = (cid & 7) << 3;
        gload_lds16(Ah + (size_t)(row0 + arow) * K_DIM + k0 + ac,
                    (void*)&As[cid * 8]);
      }
    } else {
      #pragma unroll
      for (int i = 0; i < 4; ++i) {
        const int cid = i * 256 + tid;
        const int arow = cid >> 3, ac = (cid & 7) << 3;
        const float4* p = (const float4*)(Af + (size_t)(row0 + arow) * K_DIM + k0 + ac);
        float4 a = p[0], b = p[1];
        short8 h;
        h[0] = f2bf(a.x); h[1] = f2bf(a.y); h[2] = f2bf(a.z); h[3] = f2bf(a.w);
        h[4] = f2bf(b.x); h[5] = f2bf(b.y); h[6] = f2bf(b.z); h[7] = f2bf(b.w);
        *(short8*)&As[arow * 64 + ac] = h;
      }
    }

    // ---- stage B tile [128 n][64 k] (W rows are C columns) ----
    if constexpr (PREB) {
      #pragma unroll
      for (int i = 0; i < 4; ++i) {
        const int cid = i * 256 + tid;
        const int brow = cid >> 3, bc = (cid & 7) << 3;
        gload_lds16(Bh + (size_t)(col0 + brow) * K_DIM + k0 + bc,
                    (void*)&Bs[cid * 8]);
      }
    } else {
      #pragma unroll
      for (int i = 0; i < 2; ++i) {
        const int cid = i * 256 + tid;               // 16-code chunk
        const int brow = cid >> 2, bc = (cid & 3) << 4;
        const float s = load_sc(sv, (size_t)(col0 + brow) * 64 + kt, s_is_f32);
        int codes[16];
        if (q_is_i32) {
          const int* qq = (const int*)qv + (size_t)(col0 + brow) * K_DIM + k0 + bc;
          #pragma unroll
          for (int j = 0; j < 4; ++j) {
            int4 t = ((const int4*)qq)[j];
            codes[j*4+0] = t.x; codes[j*4+1] = t.y;
            codes[j*4+2] = t.z; codes[j*4+3] = t.w;
          }
        } else {
          union { int4 v; int8_t b[16]; } u;
          u.v = *(const int4*)((const int8_t*)qv + (size_t)(col0 + brow) * K_DIM + k0 + bc);
          #pragma unroll
          for (int j = 0; j < 16; ++j) codes[j] = (int)u.b[j];
        }
        short8 h0, h1;
        #pragma unroll
        for (int j = 0; j < 8; ++j) h0[j] = f2bf((float)codes[j] * s);
        #pragma unroll
        for (int j = 0; j < 8; ++j) h1[j] = f2bf((float)codes[8 + j] * s);
        *(short8*)&Bs[brow * 64 + bc]     = h0;
        *(short8*)&Bs[brow * 64 + bc + 8] = h1;
      }
    }

    __syncthreads();   // drains vmcnt (global_load_lds) + lgkm (ds_write)

    // ---- MFMA: 16x16x32 bf16, verified fragment layout (r2) ----
    #pragma unroll
    for (int ks = 0; ks < 2; ++ks) {
      short8 a[4], b[4];
      #pragma unroll
      for (int mi = 0; mi < 4; ++mi)
        a[mi] = *(const short8*)&As[(wm * 64 + mi * 16 + lr) * 64 + ks * 32 + lk * 8];
      #pragma unroll
      for (int ni = 0; ni < 4; ++ni)
        b[ni] = *(const short8*)&Bs[(wn * 64 + ni * 16 + lr) * 64 + ks * 32 + lk * 8];
      #pragma unroll
      for (int mi = 0; mi < 4; ++mi)
        #pragma unroll
        for (int ni = 0; ni < 4; ++ni)
          acc[mi][ni] = __builtin_amdgcn_mfma_f32_16x16x32_bf16(
              a[mi], b[ni], acc[mi][ni], 0, 0, 0);
    }

    __syncthreads();
  }

  // epilogue: C/D layout col = lane&15, row = (lane>>4)*4 + reg (verified r2)
  #pragma unroll
  for (int ni = 0; ni < 4; ++ni) {
    const int col = col0 + wn * 64 + ni * 16 + lr;
    const float bvf = load_sc(bv, (size_t)col, s_is_f32);
    #pragma unroll
    for (int mi = 0; mi < 4; ++mi) {
      const int rbase = row0 + wm * 64 + mi * 16 + lk * 4;
      #pragma unroll
      for (int rr = 0; rr < 4; ++rr)
        C[(size_t)(rbase + rr) * N_DIM + col] = acc[mi][ni][rr] + bvf;
    }
  }
}

extern "C" void kernel_launch(void* const* d_in, const int* in_sizes, int n_in,
                              void* d_out, int out_size, void* d_ws, size_t ws_size,
                              hipStream_t stream) {
  const float* x  = (const float*)d_in[0];
  const void*  q  = (const void*)d_in[1];
  const void*  sc = (const void*)d_in[2];
  const void*  bs = (const void*)d_in[3];
  float* y = (float*)d_out;
  (void)in_sizes; (void)n_in; (void)out_size;

  const size_t xh_bytes = (size_t)M_DIM * K_DIM * 2;   // 64 MiB
  const size_t wq_bytes = (size_t)N_DIM * K_DIM * 2;   // ~86 MiB
  const int grid = MT_TILES * NT_TILES;                // 5504
  dim3 blk(256);

  if (ws_size >= xh_bytes + wq_bytes) {
    // fast path: both operands pre-converted, pure bf16 GEMM w/ global_load_lds
    short* xh = (short*)d_ws;
    short* wq = (short*)((char*)d_ws + xh_bytes);
    cvt_x_kernel<<<(M_DIM * K_DIM / 8) / 256, blk, 0, stream>>>(x, xh);
    deq_w_kernel<<<(N_DIM * K_DIM / 16) / 256, blk, 0, stream>>>(q, sc, wq);
    gemm_kernel<true, true><<<grid, blk, 0, stream>>>(xh, wq, q, sc, bs, y);
  } else if (ws_size >= wq_bytes) {
    // mid path: W pre-dequantized (the expensive part), x converted in-kernel
    short* wq = (short*)d_ws;
    deq_w_kernel<<<(N_DIM * K_DIM / 16) / 256, blk, 0, stream>>>(q, sc, wq);
    gemm_kernel<false, true><<<grid, blk, 0, stream>>>(x, wq, q, sc, bs, y);
  } else {
    // safe path: fully fused (round-2 verified kernel path)
    gemm_kernel<false, false><<<grid, blk, 0, stream>>>(x, nullptr, q, sc, bs, y);
  }
}

// Round 4
// 799.961 us; speedup vs baseline: 2.5416x; 1.4820x over previous
//
#include <hip/hip_runtime.h>
#include <hip/hip_fp16.h>
#include <stdint.h>

// PrunedInt4Linear: y = x @ dequant(q, scales)^T + bias
// Round 4: 256x256 tile, BK=32, 4-deep LDS ring, counted vmcnt(12) pipeline
// (T3+T4), setprio (T5), both-sides pre-swizzled LDS (T2 via packed ws),
// XCD swizzle (T1). Prep kernels write tile-packed pre-swizzled bf16 operands.

#define M_DIM 8192
#define N_DIM 11008
#define K_DIM 4096
#define MT_TILES 32            // 8192 / 256
#define NT_TILES 43            // 11008 / 256
#define K_TILES 128            // 4096 / 32
#define SLAB 8192              // shorts per (tile, kt) slab: 256 rows * 32 k

typedef short short8 __attribute__((ext_vector_type(8)));   // 8 bf16
typedef float floatx4 __attribute__((ext_vector_type(4)));

// f32 -> bf16, round-to-nearest-even
__device__ __forceinline__ unsigned short f2bf(float f) {
  union { float f; uint32_t u; } c; c.f = f;
  uint32_t u = c.u;
  return (unsigned short)((u + 0x7FFFu + ((u >> 16) & 1u)) >> 16);
}

__device__ __forceinline__ float load_sc(const void* p, size_t idx, bool is_f32) {
  if (is_f32) return ((const float*)p)[idx];
  return __half2float(((const __half*)p)[idx]);
}

// ---- dtype sniffs (verified rounds 2-3) ----
__device__ __forceinline__ bool sniff_q_is_i32(const void* qv) {
  const int* w = (const int*)qv;
  bool ok = true;
  #pragma unroll
  for (int j = 0; j < 16; ++j) {
    int v = w[j];
    ok = ok && (v == (int)(signed char)(v & 0xFF));
  }
  return ok;
}
__device__ __forceinline__ bool sniff_s_is_f32(const void* sv) {
  const float* f = (const float*)sv;
  bool ok = true;
  #pragma unroll
  for (int j = 0; j < 8; ++j) {
    float v = f[j];
    ok = ok && (v > 4e-4f) && (v < 6e-2f);
  }
  return ok;
}

// async global -> LDS, 16B per lane (dest must be wave-uniform base + lane*16)
__device__ __forceinline__ void gload_lds16(const short* g, short* l) {
  __builtin_amdgcn_global_load_lds(
      (const __attribute__((address_space(1))) uint32_t*)g,
      (__attribute__((address_space(3))) uint32_t*)l, 16, 0, 0);
}

// ============ prep: x f32 -> bf16, tile-packed + swizzled ============
// xh layout: [mt 32][kt 128][slab 8192 shorts]; element (r,k): slab short idx
//   r*32 + ((k/8) ^ ((r>>1)&3))*8 + (k%8)
__global__ __launch_bounds__(256)
void cvt_x_pack(const float* __restrict__ x, short* __restrict__ xh) {
  const int b = blockIdx.x;              // 32*256 = 8192 blocks
  const int mt = b >> 8;
  const int rem = b & 255;
  const int kt = rem >> 1, half = rem & 1;
  const int tid = threadIdx.x;
  const int r = half * 128 + (tid >> 1);
  const int s0 = (tid & 1) * 2;          // slot base (0 or 2)
  const int k0 = kt * 32 + s0 * 8;

  const float4* p = (const float4*)(x + (size_t)(mt * 256 + r) * K_DIM + k0);
  float4 f0 = p[0], f1 = p[1], f2 = p[2], f3 = p[3];
  short8 h0, h1;
  h0[0]=f2bf(f0.x); h0[1]=f2bf(f0.y); h0[2]=f2bf(f0.z); h0[3]=f2bf(f0.w);
  h0[4]=f2bf(f1.x); h0[5]=f2bf(f1.y); h0[6]=f2bf(f1.z); h0[7]=f2bf(f1.w);
  h1[0]=f2bf(f2.x); h1[1]=f2bf(f2.y); h1[2]=f2bf(f2.z); h1[3]=f2bf(f2.w);
  h1[4]=f2bf(f3.x); h1[5]=f2bf(f3.y); h1[6]=f2bf(f3.z); h1[7]=f2bf(f3.w);

  const int w = (r >> 1) & 3;
  short* slab = xh + ((size_t)mt * K_TILES + kt) * SLAB;
  *(short8*)&slab[r * 32 + ((s0    ) ^ w) * 8] = h0;
  *(short8*)&slab[r * 32 + ((s0 + 1) ^ w) * 8] = h1;
}

// ============ prep: W int4 codes + scales -> bf16, packed + swizzled ========
// wq layout: [nt 43][kt 128][slab 8192 shorts]
__global__ __launch_bounds__(256)
void deq_w_pack(const void* __restrict__ qv, const void* __restrict__ sv,
                short* __restrict__ wq) {
  const bool q_is_i32 = sniff_q_is_i32(qv);
  const bool s_is_f32 = sniff_s_is_f32(sv);
  const int b = blockIdx.x;              // 43*256 = 11008 blocks
  const int nt = b >> 8;
  const int rem = b & 255;
  const int kt = rem >> 1, half = rem & 1;
  const int tid = threadIdx.x;
  const int r = half * 128 + (tid >> 1);
  const int s0 = (tid & 1) * 2;
  const int o = nt * 256 + r;
  const int k0 = kt * 32 + s0 * 8;

  const float s = load_sc(sv, (size_t)o * 64 + (kt >> 1), s_is_f32);

  int codes[16];
  if (q_is_i32) {
    const int* qq = (const int*)qv + (size_t)o * K_DIM + k0;
    #pragma unroll
    for (int j = 0; j < 4; ++j) {
      int4 t = ((const int4*)qq)[j];
      codes[j*4+0]=t.x; codes[j*4+1]=t.y; codes[j*4+2]=t.z; codes[j*4+3]=t.w;
    }
  } else {
    union { int4 v; int8_t c[16]; } u;
    u.v = *(const int4*)((const int8_t*)qv + (size_t)o * K_DIM + k0);
    #pragma unroll
    for (int j = 0; j < 16; ++j) codes[j] = (int)u.c[j];
  }

  short8 h0, h1;
  #pragma unroll
  for (int j = 0; j < 8; ++j) h0[j] = f2bf((float)codes[j] * s);
  #pragma unroll
  for (int j = 0; j < 8; ++j) h1[j] = f2bf((float)codes[8 + j] * s);

  const int w = (r >> 1) & 3;
  short* slab = wq + ((size_t)nt * K_TILES + kt) * SLAB;
  *(short8*)&slab[r * 32 + ((s0    ) ^ w) * 8] = h0;
  *(short8*)&slab[r * 32 + ((s0 + 1) ^ w) * 8] = h1;
}

// ============ GEMM: 256x256 tile, BK=32, 8 waves, deep pipeline ============
__global__ __launch_bounds__(512, 2)
void gemm8(const short* __restrict__ xh, const short* __restrict__ wq,
           const void* __restrict__ sv, const void* __restrict__ bv,
           float* __restrict__ C) {
  __shared__ __align__(16) short lds[4 * 2 * SLAB];   // 128 KiB: 4 bufs x (A,B)

  const bool s_is_f32 = sniff_s_is_f32(sv);   // bias dtype tracks scales

  const int tid  = threadIdx.x;
  const int lane = tid & 63;
  const int wid  = tid >> 6;                  // 8 waves
  const int wm = wid >> 2, wn = wid & 3;      // 2x4 -> 128x64 out per wave
  const int lr = lane & 15, lk = lane >> 4;

  // XCD swizzle: 1376 blocks = 8 * 172; per XCD: mt fixed per 43-run (A-panel
  // 2 MB stays L2-resident across consecutive blocks).
  const int bid = blockIdx.x;
  const int xcd = bid & 7;
  const int idx = bid >> 3;                   // [0,172)
  const int mt  = xcd * 4 + idx / NT_TILES;   // [0,32)
  const int nt  = idx % NT_TILES;             // [0,43)

  const short* Aslab = xh + (size_t)mt * K_TILES * SLAB;
  const short* Bslab = wq + (size_t)nt * K_TILES * SLAB;

  // fragment LDS offsets (shorts), constant over kt; swizzle term constant too
  const int swz8 = (lk ^ ((lr >> 1) & 3)) << 3;
  int aoff[8], boff[4];
  #pragma unroll
  for (int mi = 0; mi < 8; ++mi) aoff[mi] = (wm * 128 + mi * 16 + lr) * 32 + swz8;
  #pragma unroll
  for (int ni = 0; ni < 4; ++ni) boff[ni] = (wn * 64 + ni * 16 + lr) * 32 + swz8;

  floatx4 acc[8][4];
  #pragma unroll
  for (int i = 0; i < 8; ++i)
    #pragma unroll
    for (int j = 0; j < 4; ++j)
      acc[i][j] = (floatx4){0.f, 0.f, 0.f, 0.f};

#define STAGE(t) do {                                                   \
    const short* ga_ = Aslab + (size_t)(t) * SLAB;                      \
    const short* gb_ = Bslab + (size_t)(t) * SLAB;                      \
    short* la_ = &lds[((t) & 3) * (2 * SLAB)];                          \
    short* lb_ = la_ + SLAB;                                            \
    gload_lds16(ga_ + tid * 8,        la_ + tid * 8);                   \
    gload_lds16(ga_ + 4096 + tid * 8, la_ + 4096 + tid * 8);            \
    gload_lds16(gb_ + tid * 8,        lb_ + tid * 8);                   \
    gload_lds16(gb_ + 4096 + tid * 8, lb_ + 4096 + tid * 8);            \
  } while (0)

#define COMPUTE(t) do {                                                 \
    const short* la_ = &lds[((t) & 3) * (2 * SLAB)];                    \
    const short* lb_ = la_ + SLAB;                                      \
    short8 a_[8], b_[4];                                                \
    _Pragma("unroll")                                                   \
    for (int mi = 0; mi < 8; ++mi) a_[mi] = *(const short8*)&la_[aoff[mi]]; \
    _Pragma("unroll")                                                   \
    for (int ni = 0; ni < 4; ++ni) b_[ni] = *(const short8*)&lb_[boff[ni]]; \
    __builtin_amdgcn_s_setprio(1);                                      \
    _Pragma("unroll")                                                   \
    for (int mi = 0; mi < 8; ++mi)                                      \
      _Pragma("unroll")                                                 \
      for (int ni = 0; ni < 4; ++ni)                                    \
        acc[mi][ni] = __builtin_amdgcn_mfma_f32_16x16x32_bf16(          \
            a_[mi], b_[ni], acc[mi][ni], 0, 0, 0);                      \
    __builtin_amdgcn_s_setprio(0);                                      \
  } while (0)

  // prologue: prefetch 3 K-tiles (12 VMEM ops/wave in flight)
  STAGE(0); STAGE(1); STAGE(2);

  // main loop: counted vmcnt(12) -> tile kt landed, 3 tiles stay in flight.
  // Safety: STAGE(kt+3) writes buf[(kt-1)&3], whose reads ended at barrier-B
  // of iteration kt-1 (immediately before this iteration).
  for (int kt = 0; kt < K_TILES - 3; ++kt) {
    STAGE(kt + 3);
    asm volatile("s_waitcnt vmcnt(12)" ::: "memory");
    __builtin_amdgcn_s_barrier();          // A: tile kt visible to all waves
    asm volatile("" ::: "memory");
    COMPUTE(kt);
    asm volatile("" ::: "memory");
    __builtin_amdgcn_s_barrier();          // B: reads of buf[kt&3] complete
  }

  // tail: drain 8 -> 4 -> 0 (no more staging, so no barrier-B needed)
  asm volatile("s_waitcnt vmcnt(8)" ::: "memory");
  __builtin_amdgcn_s_barrier();
  asm volatile("" ::: "memory");
  COMPUTE(K_TILES - 3);
  asm volatile("s_waitcnt vmcnt(4)" ::: "memory");
  __builtin_amdgcn_s_barrier();
  asm volatile("" ::: "memory");
  COMPUTE(K_TILES - 2);
  asm volatile("s_waitcnt vmcnt(0)" ::: "memory");
  __builtin_amdgcn_s_barrier();
  asm volatile("" ::: "memory");
  COMPUTE(K_TILES - 1);

#undef STAGE
#undef COMPUTE

  // epilogue: C/D layout col = lane&15, row = (lane>>4)*4 + reg (verified r2/r3)
  #pragma unroll
  for (int ni = 0; ni < 4; ++ni) {
    const int col = nt * 256 + wn * 64 + ni * 16 + lr;
    const float bvf = load_sc(bv, (size_t)col, s_is_f32);
    #pragma unroll
    for (int mi = 0; mi < 8; ++mi) {
      const int rbase = mt * 256 + wm * 128 + mi * 16 + lk * 4;
      #pragma unroll
      for (int rr = 0; rr < 4; ++rr)
        C[(size_t)(rbase + rr) * N_DIM + col] = acc[mi][ni][rr] + bvf;
    }
  }
}

// ============ fallback: round-2-verified fully fused kernel ============
__global__ __launch_bounds__(256)
void gemm_fused(const float* __restrict__ x, const void* __restrict__ qv,
                const void* __restrict__ sv, const void* __restrict__ bv,
                float* __restrict__ C) {
  __shared__ __align__(16) short As[128 * 64];
  __shared__ __align__(16) short Bs[128 * 64];

  const bool q_is_i32 = sniff_q_is_i32(qv);
  const bool s_is_f32 = sniff_s_is_f32(sv);

  const int tid  = threadIdx.x;
  const int lane = tid & 63;
  const int wid  = tid >> 6;
  const int wm = wid >> 1, wn = wid & 1;
  const int lr = lane & 15, lk = lane >> 4;

  const int nwg = gridDim.x;
  const int cpx = nwg >> 3;
  const int bid = blockIdx.x;
  const int swz = (bid & 7) * cpx + (bid >> 3);
  const int per_g = 4 * 86;
  const int g = swz / per_g;
  const int r = swz - g * per_g;
  const int mt = (g << 2) + (r & 3);
  const int nt = r >> 2;

  const int row0 = mt * 128;
  const int col0 = nt * 128;

  floatx4 acc[4][4];
  #pragma unroll
  for (int i = 0; i < 4; ++i)
    #pragma unroll
    for (int j = 0; j < 4; ++j)
      acc[i][j] = (floatx4){0.f, 0.f, 0.f, 0.f};

  for (int kt = 0; kt < K_DIM / 64; ++kt) {
    const int k0 = kt * 64;
    #pragma unroll
    for (int i = 0; i < 4; ++i) {
      const int cid = i * 256 + tid;
      const int arow = cid >> 3, ac = (cid & 7) << 3;
      const float4* p = (const float4*)(x + (size_t)(row0 + arow) * K_DIM + k0 + ac);
      float4 a = p[0], b = p[1];
      short8 h;
      h[0]=f2bf(a.x); h[1]=f2bf(a.y); h[2]=f2bf(a.z); h[3]=f2bf(a.w);
      h[4]=f2bf(b.x); h[5]=f2bf(b.y); h[6]=f2bf(b.z); h[7]=f2bf(b.w);
      *(short8*)&As[arow * 64 + ac] = h;
    }
    #pragma unroll
    for (int i = 0; i < 2; ++i) {
      const int cid = i * 256 + tid;
      const int brow = cid >> 2, bc = (cid & 3) << 4;
      const float s = load_sc(sv, (size_t)(col0 + brow) * 64 + kt, s_is_f32);
      int codes[16];
      if (q_is_i32) {
        const int* qq = (const int*)qv + (size_t)(col0 + brow) * K_DIM + k0 + bc;
        #pragma unroll
        for (int j = 0; j < 4; ++j) {
          int4 t = ((const int4*)qq)[j];
          codes[j*4+0]=t.x; codes[j*4+1]=t.y; codes[j*4+2]=t.z; codes[j*4+3]=t.w;
        }
      } else {
        union { int4 v; int8_t c[16]; } u;
        u.v = *(const int4*)((const int8_t*)qv + (size_t)(col0 + brow) * K_DIM + k0 + bc);
        #pragma unroll
        for (int j = 0; j < 16; ++j) codes[j] = (int)u.c[j];
      }
      short8 h0, h1;
      #pragma unroll
      for (int j = 0; j < 8; ++j) h0[j] = f2bf((float)codes[j] * s);
      #pragma unroll
      for (int j = 0; j < 8; ++j) h1[j] = f2bf((float)codes[8 + j] * s);
      *(short8*)&Bs[brow * 64 + bc]     = h0;
      *(short8*)&Bs[brow * 64 + bc + 8] = h1;
    }
    __syncthreads();
    #pragma unroll
    for (int ks = 0; ks < 2; ++ks) {
      short8 a[4], b[4];
      #pragma unroll
      for (int mi = 0; mi < 4; ++mi)
        a[mi] = *(const short8*)&As[(wm * 64 + mi * 16 + lr) * 64 + ks * 32 + lk * 8];
      #pragma unroll
      for (int ni = 0; ni < 4; ++ni)
        b[ni] = *(const short8*)&Bs[(wn * 64 + ni * 16 + lr) * 64 + ks * 32 + lk * 8];
      #pragma unroll
      for (int mi = 0; mi < 4; ++mi)
        #pragma unroll
        for (int ni = 0; ni < 4; ++ni)
          acc[mi][ni] = __builtin_amdgcn_mfma_f32_16x16x32_bf16(
              a[mi], b[ni], acc[mi][ni], 0, 0, 0);
    }
    __syncthreads();
  }

  #pragma unroll
  for (int ni = 0; ni < 4; ++ni) {
    const int col = col0 + wn * 64 + ni * 16 + lr;
    const float bvf = load_sc(bv, (size_t)col, s_is_f32);
    #pragma unroll
    for (int mi = 0; mi < 4; ++mi) {
      const int rbase = row0 + wm * 64 + mi * 16 + lk * 4;
      #pragma unroll
      for (int rr = 0; rr < 4; ++rr)
        C[(size_t)(rbase + rr) * N_DIM + col] = acc[mi][ni][rr] + bvf;
    }
  }
}

extern "C" void kernel_launch(void* const* d_in, const int* in_sizes, int n_in,
                              void* d_out, int out_size, void* d_ws, size_t ws_size,
                              hipStream_t stream) {
  const float* x  = (const float*)d_in[0];
  const void*  q  = (const void*)d_in[1];
  const void*  sc = (const void*)d_in[2];
  const void*  bs = (const void*)d_in[3];
  float* y = (float*)d_out;
  (void)in_sizes; (void)n_in; (void)out_size;

  const size_t xh_bytes = (size_t)M_DIM * K_DIM * 2;   // 64 MiB
  const size_t wq_bytes = (size_t)N_DIM * K_DIM * 2;   // ~86 MiB

  if (ws_size >= xh_bytes + wq_bytes) {   // confirmed available in round 3
    short* xh = (short*)d_ws;
    short* wq = (short*)((char*)d_ws + xh_bytes);
    cvt_x_pack<<<MT_TILES * 256, dim3(256), 0, stream>>>(x, xh);
    deq_w_pack<<<NT_TILES * 256, dim3(256), 0, stream>>>(q, sc, wq);
    gemm8<<<MT_TILES * NT_TILES * 8 / 8, dim3(512), 0, stream>>>(xh, wq, sc, bs, y);
  } else {
    gemm_fused<<<(M_DIM / 128) * (N_DIM / 128), dim3(256), 0, stream>>>(x, q, sc, bs, y);
  }
}

// Round 6
// 761.846 us; speedup vs baseline: 2.6687x; 1.0500x over previous
//
#include <hip/hip_runtime.h>
#include <hip/hip_fp16.h>
#include <stdint.h>

// PrunedInt4Linear: y = x @ dequant(q, scales)^T + bias
// Round 6: r5's race fixed. Pipeline order per K-step is now
//   vmcnt(4) -> s_barrier -> STAGE(kt+3) -> LOADF(kt+1) -> DOMFMA(kt)
// so every LDS read of tile t happens AFTER the barrier that publishes all
// waves' tile-t staging (r5 read before the barrier -> NaN). One barrier per
// K-step; ds_reads of the next tile overlap the MFMA cluster of the current.
// Keeps r4-verified prep (packed + pre-swizzled ws), nt-major XCD dispatch.

#define M_DIM 8192
#define N_DIM 11008
#define K_DIM 4096
#define MT_TILES 32            // 8192 / 256
#define NT_TILES 43            // 11008 / 256
#define K_TILES 128            // 4096 / 32
#define SLAB 8192              // shorts per (tile, kt) slab: 256 rows * 32 k

typedef short short8 __attribute__((ext_vector_type(8)));   // 8 bf16
typedef float floatx4 __attribute__((ext_vector_type(4)));

// f32 -> bf16, round-to-nearest-even
__device__ __forceinline__ unsigned short f2bf(float f) {
  union { float f; uint32_t u; } c; c.f = f;
  uint32_t u = c.u;
  return (unsigned short)((u + 0x7FFFu + ((u >> 16) & 1u)) >> 16);
}

__device__ __forceinline__ float load_sc(const void* p, size_t idx, bool is_f32) {
  if (is_f32) return ((const float*)p)[idx];
  return __half2float(((const __half*)p)[idx]);
}

// ---- dtype sniffs (verified rounds 2-4) ----
__device__ __forceinline__ bool sniff_q_is_i32(const void* qv) {
  const int* w = (const int*)qv;
  bool ok = true;
  #pragma unroll
  for (int j = 0; j < 16; ++j) {
    int v = w[j];
    ok = ok && (v == (int)(signed char)(v & 0xFF));
  }
  return ok;
}
__device__ __forceinline__ bool sniff_s_is_f32(const void* sv) {
  const float* f = (const float*)sv;
  bool ok = true;
  #pragma unroll
  for (int j = 0; j < 8; ++j) {
    float v = f[j];
    ok = ok && (v > 4e-4f) && (v < 6e-2f);
  }
  return ok;
}

// async global -> LDS, 16B per lane (dest = wave-uniform base + lane*16)
__device__ __forceinline__ void gload_lds16(const short* g, short* l) {
  __builtin_amdgcn_global_load_lds(
      (const __attribute__((address_space(1))) uint32_t*)g,
      (__attribute__((address_space(3))) uint32_t*)l, 16, 0, 0);
}

// ============ prep: x f32 -> bf16, tile-packed + swizzled (r4-verified) ====
// xh layout: [mt 32][kt 128][slab 8192 shorts]; element (r,k): slab short idx
//   r*32 + ((k/8) ^ ((r>>1)&3))*8 + (k%8)
__global__ __launch_bounds__(256)
void cvt_x_pack(const float* __restrict__ x, short* __restrict__ xh) {
  const int b = blockIdx.x;              // 32*256 = 8192 blocks
  const int mt = b >> 8;
  const int rem = b & 255;
  const int kt = rem >> 1, half = rem & 1;
  const int tid = threadIdx.x;
  const int r = half * 128 + (tid >> 1);
  const int s0 = (tid & 1) * 2;          // slot base (0 or 2)
  const int k0 = kt * 32 + s0 * 8;

  const float4* p = (const float4*)(x + (size_t)(mt * 256 + r) * K_DIM + k0);
  float4 f0 = p[0], f1 = p[1], f2 = p[2], f3 = p[3];
  short8 h0, h1;
  h0[0]=f2bf(f0.x); h0[1]=f2bf(f0.y); h0[2]=f2bf(f0.z); h0[3]=f2bf(f0.w);
  h0[4]=f2bf(f1.x); h0[5]=f2bf(f1.y); h0[6]=f2bf(f1.z); h0[7]=f2bf(f1.w);
  h1[0]=f2bf(f2.x); h1[1]=f2bf(f2.y); h1[2]=f2bf(f2.z); h1[3]=f2bf(f2.w);
  h1[4]=f2bf(f3.x); h1[5]=f2bf(f3.y); h1[6]=f2bf(f3.z); h1[7]=f2bf(f3.w);

  const int w = (r >> 1) & 3;
  short* slab = xh + ((size_t)mt * K_TILES + kt) * SLAB;
  *(short8*)&slab[r * 32 + ((s0    ) ^ w) * 8] = h0;
  *(short8*)&slab[r * 32 + ((s0 + 1) ^ w) * 8] = h1;
}

// ============ prep: W int4 codes + scales -> bf16, packed + swizzled =======
// wq layout: [nt 43][kt 128][slab 8192 shorts]
__global__ __launch_bounds__(256)
void deq_w_pack(const void* __restrict__ qv, const void* __restrict__ sv,
                short* __restrict__ wq) {
  const bool q_is_i32 = sniff_q_is_i32(qv);
  const bool s_is_f32 = sniff_s_is_f32(sv);
  const int b = blockIdx.x;              // 43*256 = 11008 blocks
  const int nt = b >> 8;
  const int rem = b & 255;
  const int kt = rem >> 1, half = rem & 1;
  const int tid = threadIdx.x;
  const int r = half * 128 + (tid >> 1);
  const int s0 = (tid & 1) * 2;
  const int o = nt * 256 + r;
  const int k0 = kt * 32 + s0 * 8;

  const float s = load_sc(sv, (size_t)o * 64 + (kt >> 1), s_is_f32);

  int codes[16];
  if (q_is_i32) {
    const int* qq = (const int*)qv + (size_t)o * K_DIM + k0;
    #pragma unroll
    for (int j = 0; j < 4; ++j) {
      int4 t = ((const int4*)qq)[j];
      codes[j*4+0]=t.x; codes[j*4+1]=t.y; codes[j*4+2]=t.z; codes[j*4+3]=t.w;
    }
  } else {
    union { int4 v; int8_t c[16]; } u;
    u.v = *(const int4*)((const int8_t*)qv + (size_t)o * K_DIM + k0);
    #pragma unroll
    for (int j = 0; j < 16; ++j) codes[j] = (int)u.c[j];
  }

  short8 h0, h1;
  #pragma unroll
  for (int j = 0; j < 8; ++j) h0[j] = f2bf((float)codes[j] * s);
  #pragma unroll
  for (int j = 0; j < 8; ++j) h1[j] = f2bf((float)codes[8 + j] * s);

  const int w = (r >> 1) & 3;
  short* slab = wq + ((size_t)nt * K_TILES + kt) * SLAB;
  *(short8*)&slab[r * 32 + ((s0    ) ^ w) * 8] = h0;
  *(short8*)&slab[r * 32 + ((s0 + 1) ^ w) * 8] = h1;
}

// ============ GEMM: 256x256 tile, BK=32, 8 waves, frag-dbuf pipeline =======
__global__ __launch_bounds__(512)
void gemm8(const short* __restrict__ xh, const short* __restrict__ wq,
           const void* __restrict__ sv, const void* __restrict__ bv,
           float* __restrict__ C) {
  __shared__ __align__(16) short lds[4 * 2 * SLAB];   // 128 KiB: 4 bufs x (A,B)

  const bool s_is_f32 = sniff_s_is_f32(sv);   // bias dtype tracks scales

  const int tid  = threadIdx.x;
  const int lane = tid & 63;
  const int wid  = tid >> 6;                  // 8 waves
  const int wm = wid >> 2, wn = wid & 3;      // 2x4 -> 128x64 out per wave
  const int lr = lane & 15, lk = lane >> 4;

  // nt-major dispatch: all XCDs sweep the same nt window concurrently ->
  // B-panel fetched once (shared via L3), full A (64 MB) stays L3-resident.
  const int bid = blockIdx.x;
  const int xcd = bid & 7;
  const int seq = bid >> 3;                   // [0,172)
  const int nt  = seq >> 2;                   // [0,43)
  const int mt  = xcd * 4 + (seq & 3);        // [0,32)

  const short* Aslab = xh + (size_t)mt * K_TILES * SLAB;
  const short* Bslab = wq + (size_t)nt * K_TILES * SLAB;

  // fragment LDS offsets (shorts), constant over kt (r4-verified, 0 conflicts)
  const int swz8 = (lk ^ ((lr >> 1) & 3)) << 3;
  int aoff[8], boff[4];
  #pragma unroll
  for (int mi = 0; mi < 8; ++mi) aoff[mi] = (wm * 128 + mi * 16 + lr) * 32 + swz8;
  #pragma unroll
  for (int ni = 0; ni < 4; ++ni) boff[ni] = (wn * 64 + ni * 16 + lr) * 32 + swz8;

  floatx4 acc[8][4];
  #pragma unroll
  for (int i = 0; i < 8; ++i)
    #pragma unroll
    for (int j = 0; j < 4; ++j)
      acc[i][j] = (floatx4){0.f, 0.f, 0.f, 0.f};

  short8 fa[8], fb[4], ga[8], gb[4];   // two named frag sets (rule #20)

#define STAGE(t) do {                                                   \
    const short* gA_ = Aslab + (size_t)(t) * SLAB;                      \
    const short* gB_ = Bslab + (size_t)(t) * SLAB;                      \
    short* lA_ = &lds[((t) & 3) * (2 * SLAB)];                          \
    short* lB_ = lA_ + SLAB;                                            \
    gload_lds16(gA_ + tid * 8,        lA_ + tid * 8);                   \
    gload_lds16(gA_ + 4096 + tid * 8, lA_ + 4096 + tid * 8);            \
    gload_lds16(gB_ + tid * 8,        lB_ + tid * 8);                   \
    gload_lds16(gB_ + 4096 + tid * 8, lB_ + 4096 + tid * 8);            \
  } while (0)

#define LOADF(da, db, t) do {                                           \
    const short* lA_ = &lds[((t) & 3) * (2 * SLAB)];                    \
    const short* lB_ = lA_ + SLAB;                                      \
    _Pragma("unroll")                                                   \
    for (int mi = 0; mi < 8; ++mi) da[mi] = *(const short8*)&lA_[aoff[mi]]; \
    _Pragma("unroll")                                                   \
    for (int ni = 0; ni < 4; ++ni) db[ni] = *(const short8*)&lB_[boff[ni]]; \
  } while (0)

#define DOMFMA(sa, sb) do {                                             \
    __builtin_amdgcn_s_setprio(1);                                      \
    _Pragma("unroll")                                                   \
    for (int mi = 0; mi < 8; ++mi)                                      \
      _Pragma("unroll")                                                 \
      for (int ni = 0; ni < 4; ++ni)                                    \
        acc[mi][ni] = __builtin_amdgcn_mfma_f32_16x16x32_bf16(          \
            sa[mi], sb[ni], acc[mi][ni], 0, 0, 0);                      \
    __builtin_amdgcn_s_setprio(0);                                      \
  } while (0)

#define FENCE asm volatile("" ::: "memory")
#define VMCNT(n) asm volatile("s_waitcnt vmcnt(" #n ")" ::: "memory")
#define BARRIER do { FENCE; __builtin_amdgcn_s_barrier(); FENCE; } while (0)

  // prologue: stage 3 tiles (12 loads/wave outstanding); publish+read tile 0
  STAGE(0); STAGE(1); STAGE(2);
  VMCNT(8);                    // own tile-0 loads retired
  BARRIER;                     // tile 0 published to all waves
  LOADF(fa, fb, 0);

  // Steady state, 2 tiles per loop iter, ONE barrier per tile.
  // Per phase (tile kt current, fa/ga alternate):
  //   VMCNT(4): retire own tile-(kt+1) staging loads (2 tiles in flight)
  //   BARRIER : all waves retired tile kt+1 -> published       (r5 fix:
  //             the LDS read of kt+1 is now AFTER this barrier)
  //   STAGE(kt+3): overwrite buf (kt-1)&3 -- its reads were lgkm-retired
  //             before each wave crossed THIS barrier; disjoint from the
  //             buf (kt+1)&3 being read below.
  //   LOADF(kt+1): ds_reads fly in parallel with...
  //   DOMFMA(kt): 32 MFMAs on frags read last phase (no lgkm dep on LOADF)
  for (int kt = 0; kt < 124; kt += 2) {
    VMCNT(4);
    BARRIER;
    STAGE(kt + 3);
    LOADF(ga, gb, kt + 1);
    DOMFMA(fa, fb);            // tile kt
    VMCNT(4);
    BARRIER;
    STAGE(kt + 4);
    LOADF(fa, fb, kt + 2);
    DOMFMA(ga, gb);            // tile kt+1
  }

  // tail: staged through 126; fa holds tile 124.
  VMCNT(4);                    // retire 125
  BARRIER;
  STAGE(127);
  LOADF(ga, gb, 125);
  DOMFMA(fa, fb);              // 124
  VMCNT(4);                    // retire 126
  BARRIER;
  LOADF(fa, fb, 126);
  DOMFMA(ga, gb);              // 125
  VMCNT(0);                    // retire 127
  BARRIER;
  LOADF(ga, gb, 127);
  DOMFMA(fa, fb);              // 126
  DOMFMA(ga, gb);              // 127

#undef STAGE
#undef LOADF
#undef DOMFMA
#undef FENCE
#undef VMCNT
#undef BARRIER

  // epilogue: C/D layout col = lane&15, row = (lane>>4)*4 + reg (verified)
  #pragma unroll
  for (int ni = 0; ni < 4; ++ni) {
    const int col = nt * 256 + wn * 64 + ni * 16 + lr;
    const float bvf = load_sc(bv, (size_t)col, s_is_f32);
    #pragma unroll
    for (int mi = 0; mi < 8; ++mi) {
      const int rbase = mt * 256 + wm * 128 + mi * 16 + lk * 4;
      #pragma unroll
      for (int rr = 0; rr < 4; ++rr)
        C[(size_t)(rbase + rr) * N_DIM + col] = acc[mi][ni][rr] + bvf;
    }
  }
}

// ============ fallback: round-2-verified fully fused kernel ============
__global__ __launch_bounds__(256)
void gemm_fused(const float* __restrict__ x, const void* __restrict__ qv,
                const void* __restrict__ sv, const void* __restrict__ bv,
                float* __restrict__ C) {
  __shared__ __align__(16) short As[128 * 64];
  __shared__ __align__(16) short Bs[128 * 64];

  const bool q_is_i32 = sniff_q_is_i32(qv);
  const bool s_is_f32 = sniff_s_is_f32(sv);

  const int tid  = threadIdx.x;
  const int lane = tid & 63;
  const int wid  = tid >> 6;
  const int wm = wid >> 1, wn = wid & 1;
  const int lr = lane & 15, lk = lane >> 4;

  const int nwg = gridDim.x;
  const int cpx = nwg >> 3;
  const int bid = blockIdx.x;
  const int swz = (bid & 7) * cpx + (bid >> 3);
  const int per_g = 4 * 86;
  const int g = swz / per_g;
  const int r = swz - g * per_g;
  const int mt = (g << 2) + (r & 3);
  const int nt = r >> 2;

  const int row0 = mt * 128;
  const int col0 = nt * 128;

  floatx4 acc[4][4];
  #pragma unroll
  for (int i = 0; i < 4; ++i)
    #pragma unroll
    for (int j = 0; j < 4; ++j)
      acc[i][j] = (floatx4){0.f, 0.f, 0.f, 0.f};

  for (int kt = 0; kt < K_DIM / 64; ++kt) {
    const int k0 = kt * 64;
    #pragma unroll
    for (int i = 0; i < 4; ++i) {
      const int cid = i * 256 + tid;
      const int arow = cid >> 3, ac = (cid & 7) << 3;
      const float4* p = (const float4*)(x + (size_t)(row0 + arow) * K_DIM + k0 + ac);
      float4 a = p[0], b = p[1];
      short8 h;
      h[0]=f2bf(a.x); h[1]=f2bf(a.y); h[2]=f2bf(a.z); h[3]=f2bf(a.w);
      h[4]=f2bf(b.x); h[5]=f2bf(b.y); h[6]=f2bf(b.z); h[7]=f2bf(b.w);
      *(short8*)&As[arow * 64 + ac] = h;
    }
    #pragma unroll
    for (int i = 0; i < 2; ++i) {
      const int cid = i * 256 + tid;
      const int brow = cid >> 2, bc = (cid & 3) << 4;
      const float s = load_sc(sv, (size_t)(col0 + brow) * 64 + kt, s_is_f32);
      int codes[16];
      if (q_is_i32) {
        const int* qq = (const int*)qv + (size_t)(col0 + brow) * K_DIM + k0 + bc;
        #pragma unroll
        for (int j = 0; j < 4; ++j) {
          int4 t = ((const int4*)qq)[j];
          codes[j*4+0]=t.x; codes[j*4+1]=t.y; codes[j*4+2]=t.z; codes[j*4+3]=t.w;
        }
      } else {
        union { int4 v; int8_t c[16]; } u;
        u.v = *(const int4*)((const int8_t*)qv + (size_t)(col0 + brow) * K_DIM + k0 + bc);
        #pragma unroll
        for (int j = 0; j < 16; ++j) codes[j] = (int)u.c[j];
      }
      short8 h0, h1;
      #pragma unroll
      for (int j = 0; j < 8; ++j) h0[j] = f2bf((float)codes[j] * s);
      #pragma unroll
      for (int j = 0; j < 8; ++j) h1[j] = f2bf((float)codes[8 + j] * s);
      *(short8*)&Bs[brow * 64 + bc]     = h0;
      *(short8*)&Bs[brow * 64 + bc + 8] = h1;
    }
    __syncthreads();
    #pragma unroll
    for (int ks = 0; ks < 2; ++ks) {
      short8 a[4], b[4];
      #pragma unroll
      for (int mi = 0; mi < 4; ++mi)
        a[mi] = *(const short8*)&As[(wm * 64 + mi * 16 + lr) * 64 + ks * 32 + lk * 8];
      #pragma unroll
      for (int ni = 0; ni < 4; ++ni)
        b[ni] = *(const short8*)&Bs[(wn * 64 + ni * 16 + lr) * 64 + ks * 32 + lk * 8];
      #pragma unroll
      for (int mi = 0; mi < 4; ++mi)
        #pragma unroll
        for (int ni = 0; ni < 4; ++ni)
          acc[mi][ni] = __builtin_amdgcn_mfma_f32_16x16x32_bf16(
              a[mi], b[ni], acc[mi][ni], 0, 0, 0);
    }
    __syncthreads();
  }

  #pragma unroll
  for (int ni = 0; ni < 4; ++ni) {
    const int col = col0 + wn * 64 + ni * 16 + lr;
    const float bvf = load_sc(bv, (size_t)col, s_is_f32);
    #pragma unroll
    for (int mi = 0; mi < 4; ++mi) {
      const int rbase = row0 + wm * 64 + mi * 16 + lk * 4;
      #pragma unroll
      for (int rr = 0; rr < 4; ++rr)
        C[(size_t)(rbase + rr) * N_DIM + col] = acc[mi][ni][rr] + bvf;
    }
  }
}

extern "C" void kernel_launch(void* const* d_in, const int* in_sizes, int n_in,
                              void* d_out, int out_size, void* d_ws, size_t ws_size,
                              hipStream_t stream) {
  const float* x  = (const float*)d_in[0];
  const void*  q  = (const void*)d_in[1];
  const void*  sc = (const void*)d_in[2];
  const void*  bs = (const void*)d_in[3];
  float* y = (float*)d_out;
  (void)in_sizes; (void)n_in; (void)out_size;

  const size_t xh_bytes = (size_t)M_DIM * K_DIM * 2;   // 64 MiB
  const size_t wq_bytes = (size_t)N_DIM * K_DIM * 2;   // ~86 MiB

  if (ws_size >= xh_bytes + wq_bytes) {   // confirmed available (r3/r4)
    short* xh = (short*)d_ws;
    short* wq = (short*)((char*)d_ws + xh_bytes);
    cvt_x_pack<<<MT_TILES * 256, dim3(256), 0, stream>>>(x, xh);
    deq_w_pack<<<NT_TILES * 256, dim3(256), 0, stream>>>(q, sc, wq);
    gemm8<<<MT_TILES * NT_TILES, dim3(512), 0, stream>>>(xh, wq, sc, bs, y);
  } else {
    gemm_fused<<<(M_DIM / 128) * (N_DIM / 128), dim3(256), 0, stream>>>(x, q, sc, bs, y);
  }
}